// Round 13
// baseline (6192.112 us; speedup 1.0000x reference)
//
#include <hip/hip_runtime.h>
#include <stdint.h>

#define NB    64
#define NN    131072
#define NPTS  1024
#define TPB   512                  // 8 waves, 1 block/CU (proven geometry)
#define WPB   4                    // workgroups per batch
#define NWAVE (TPB / 64)           // 8
#define NSLOT (WPB * NWAVE)        // 32 wave-level slots per (batch, round)
#define CHUNK (NN / WPB)           // 32768 points per wg
#define PPT   (CHUNK / TPB)        // 64 points per thread
#define RPTS  40                   // register-resident points/thread
#define LPTS  24                   // LDS-resident points/thread (147456 B)
#define RPAIR (RPTS / 2)           // 20
#define LPAIR (LPTS / 2)           // 12
#define NPAIR (PPT / 2)            // 32 pairs, 4 scan-blocks of 8

typedef float v2f __attribute__((ext_vector_type(2)));
typedef unsigned long long u64;

static __device__ __forceinline__ v2f vmin2(v2f a, v2f b) {
#if __has_builtin(__builtin_elementwise_min)
    return __builtin_elementwise_min(a, b);
#else
    v2f r; r.x = fminf(a.x, b.x); r.y = fminf(a.y, b.y); return r;
#endif
}
static __device__ __forceinline__ v2f vmax2(v2f a, v2f b) {
#if __has_builtin(__builtin_elementwise_max)
    return __builtin_elementwise_max(a, b);
#else
    v2f r; r.x = fmaxf(a.x, b.x); r.y = fmaxf(a.y, b.y); return r;
#endif
}

// ---------------- inter-wg protocol: relaxed + cold slots ----------
// Key: [dist_bits:32 | ~idx:32]; u64 max == (max dist, then min idx) ==
// jnp.argmax first-occurrence. ~idx != 0 -> nonzero is the publish flag
// (slots memset once per launch).
// HW LESSONS: RELAXED atomics only (R4: acq/rel at agent scope = cache-
// maintenance storm, 118x). Never reuse a spin address within a launch (R5).
// No multi-line payload spins (R8/R11 regressed: every extra polled word is
// an extra serial MALL trip; the uniform cached P[widx] reload is cheaper).
// WS32 (R13): wave-level publish -> 32 slots per (batch,round) in ONE 256B
// block; lane L polls slot L&31 (coalesced to 4 lines); 5-level butterfly
// replaces LDS block-reduce + cross-wg combine; NO __syncthreads in the loop
// (LDS points are own-thread-read-only; waves drift <= 1 round; per-k slots).
// COMPUTE (R11/R12-proven): pure packed hot loop, block-max accumulators,
// block-skipped equality scan, split float-max / u32-min wave reduces.
// R13 adds a depth-3 LDS prefetch pipeline interleaved with reg pairs.

template <bool WS32>
__global__ __launch_bounds__(TPB)
__attribute__((amdgpu_waves_per_eu(2, 2)))
void fps_kernel(
    const float* __restrict__ pos,
    const int*   __restrict__ start_p,
    int*         __restrict__ out,
    u64*         __restrict__ slots)
{
#pragma clang fp contract(off)
    const int wg   = blockIdx.x;
    const int xcd  = wg & 7;            // heuristic: keep a batch's 4 wgs on one XCD
    const int sl   = wg >> 3;
    const int b    = xcd * 8 + (sl >> 2);
    const int r    = sl & 3;
    const int t    = threadIdx.x;
    const int lane = t & 63;
    const int wv   = t >> 6;

    const float* __restrict__ P  = pos + (size_t)b * NN * 3;
    const float* __restrict__ Pc = P + (size_t)r * CHUNK * 3;
    u64* __restrict__ bslots = slots + (size_t)b * NPTS * (WS32 ? NSLOT : WPB);

    // pair-packed LDS: coords of points (2l, 2l+1) adjacent -> ds_read_b64
    __shared__ float lx[LPAIR * TPB * 2];   // 49152 B
    __shared__ float ly[LPAIR * TPB * 2];
    __shared__ float lz[LPAIR * TPB * 2];   // 147456 B total
    __shared__ u64   wred[2][NWAVE];        // used only in the !WS32 fallback

    // ---- one-time staging: j<40 -> regs, j in [40,64) -> LDS (own-thread only) ----
    v2f rx[RPAIR], ry[RPAIR], rz[RPAIR];
#pragma unroll
    for (int p = 0; p < RPAIR; ++p) {
        const float* a = Pc + (size_t)(t + (2 * p) * TPB) * 3;
        const float* c = a + (size_t)TPB * 3;
        rx[p] = (v2f){a[0], c[0]};
        ry[p] = (v2f){a[1], c[1]};
        rz[p] = (v2f){a[2], c[2]};
    }
#pragma unroll
    for (int l = 0; l < LPAIR; ++l) {
        const float* a = Pc + (size_t)(t + (RPTS + 2 * l) * TPB) * 3;
        const float* c = a + (size_t)TPB * 3;
        const int idx = (l * TPB + t) * 2;
        lx[idx] = a[0]; lx[idx + 1] = c[0];   // same-thread RAW only: no barrier
        ly[idx] = a[1]; ly[idx + 1] = c[1];
        lz[idx] = a[2]; lz[idx + 1] = c[2];
    }

    const int start = start_p[0];
    float sx = P[(size_t)start * 3 + 0];
    float sy = P[(size_t)start * 3 + 1];
    float sz = P[(size_t)start * 3 + 2];
    if (r == 0 && t == 0) out[(size_t)b * NPTS] = start;

    v2f dist[NPAIR];
#pragma unroll
    for (int p = 0; p < NPAIR; ++p)
        dist[p] = (v2f){__builtin_inff(), __builtin_inff()};

    const unsigned bt = (unsigned)(r * CHUNK + t);

    for (int k = 1; k < NPTS; ++k) {
        const v2f s0 = (v2f){sx, sx}, s1 = (v2f){sy, sy}, s2 = (v2f){sz, sz};

        v2f vb[4];
#pragma unroll
        for (int q = 0; q < 4; ++q) vb[q] = (v2f){-1.0f, -1.0f};

        // exact per-op rounding: (dx*dx + dy*dy) + dz*dz, contract off
#define PAIR_STEP(DP, PX, PY, PZ)                                        \
        {                                                                \
            v2f dx = (PX) - s0, dy = (PY) - s1, dz = (PZ) - s2;          \
            v2f d  = (dx * dx + dy * dy) + dz * dz;                      \
            v2f nd = vmin2(dist[DP], d);                                 \
            dist[DP] = nd;                                               \
            vb[(DP) >> 3] = vmax2(vb[(DP) >> 3], nd);                    \
        }

        // depth-3 LDS prefetch pipeline, interleaved with reg pairs
        v2f bx[3], by[3], bz[3];
#pragma unroll
        for (int l = 0; l < 3; ++l) {
            const int idx = (l * TPB + t) * 2;
            bx[l] = *reinterpret_cast<const v2f*>(&lx[idx]);
            by[l] = *reinterpret_cast<const v2f*>(&ly[idx]);
            bz[l] = *reinterpret_cast<const v2f*>(&lz[idx]);
        }
#pragma unroll
        for (int l = 0; l < LPAIR; ++l) {
            const int cur = l % 3;                  // compile-time under unroll
            PAIR_STEP(RPAIR + l, bx[cur], by[cur], bz[cur]);
            if (l + 3 < LPAIR) {                    // prefetch 3 groups ahead
                const int idx = ((l + 3) * TPB + t) * 2;
                bx[cur] = *reinterpret_cast<const v2f*>(&lx[idx]);
                by[cur] = *reinterpret_cast<const v2f*>(&ly[idx]);
                bz[cur] = *reinterpret_cast<const v2f*>(&lz[idx]);
            }
            if (l < 8) {                            // 2 reg pairs per iteration
                PAIR_STEP(2 * l,     rx[2 * l],     ry[2 * l],     rz[2 * l]);
                PAIR_STEP(2 * l + 1, rx[2 * l + 1], ry[2 * l + 1], rz[2 * l + 1]);
            } else {                                // last 4 iterations: 1 pair
                PAIR_STEP(16 + (l - 8), rx[16 + (l - 8)],
                          ry[16 + (l - 8)], rz[16 + (l - 8)]);
            }
        }
#undef PAIR_STEP

        // block maxes -> wave-uniform best (float reduce, cheap)
        float m[4];
#pragma unroll
        for (int q = 0; q < 4; ++q) m[q] = fmaxf(vb[q].x, vb[q].y);
        float wbest = fmaxf(fmaxf(m[0], m[1]), fmaxf(m[2], m[3]));
#pragma unroll
        for (int o = 32; o >= 1; o >>= 1)
            wbest = fmaxf(wbest, __shfl_xor(wbest, o, 64));

        // block-skipped equality scan: recover lane-local first index
        unsigned biL = 0xFFFFFFFFu;
#pragma unroll
        for (int q = 0; q < 4; ++q) {
            if (__any(m[q] == wbest)) {
#pragma unroll
                for (int p = 8 * q; p < 8 * q + 8; ++p) {
                    if (dist[p].x == wbest)
                        biL = min(biL, bt + (unsigned)((2 * p) * TPB));
                    if (dist[p].y == wbest)
                        biL = min(biL, bt + (unsigned)((2 * p + 1) * TPB));
                }
            }
        }

        // u32 min-reduce of index across the wave (wbest already uniform)
        unsigned bw = biL;
#pragma unroll
        for (int o = 32; o >= 1; o >>= 1) {
            unsigned q = (unsigned)__shfl_xor((int)bw, o, 64);
            bw = min(bw, q);
        }

        const u64 pk = ((u64)__float_as_uint(wbest) << 32) | (unsigned)~bw;

        u64 g;
        if constexpr (WS32) {
            // ---- barrier-free: wave-level publish + 32-slot butterfly ----
            if (lane == 0)
                __hip_atomic_store(&bslots[(size_t)k * NSLOT + r * NWAVE + wv], pk,
                                   __ATOMIC_RELAXED, __HIP_MEMORY_SCOPE_AGENT);
            // lane L polls slot (k, L&31): 256B block -> 4 coalesced lines
            const u64* sp = &bslots[(size_t)k * NSLOT + (lane & (NSLOT - 1))];
            for (;;) {
                g = __hip_atomic_load(sp, __ATOMIC_RELAXED, __HIP_MEMORY_SCOPE_AGENT);
                if (g) break;
                __builtin_amdgcn_s_sleep(1);
            }
#pragma unroll
            for (int o = 1; o <= 16; o <<= 1) {     // 5-level butterfly over 32
                u64 q = __shfl_xor(g, o, 64);
                if (q > g) g = q;
            }
        } else {
            // ---- R12-exact fallback: wred + barrier + 4-slot combine ----
            const int bank = k & 1;
            if (lane == 0) wred[bank][wv] = pk;
            __syncthreads();
            u64 v = wred[bank][lane & (NWAVE - 1)];
#pragma unroll
            for (int o = 1; o < NWAVE; o <<= 1) {
                u64 q = __shfl_xor(v, o, 64);
                if (q > v) v = q;
            }
            if (t == 0)
                __hip_atomic_store(&bslots[(size_t)k * WPB + r], v,
                                   __ATOMIC_RELAXED, __HIP_MEMORY_SCOPE_AGENT);
            const u64* sp = &bslots[(size_t)k * WPB + (lane & 3)];
            for (;;) {
                g = __hip_atomic_load(sp, __ATOMIC_RELAXED, __HIP_MEMORY_SCOPE_AGENT);
                if (g) break;
                __builtin_amdgcn_s_sleep(1);
            }
#pragma unroll
            for (int o = 1; o <= 2; o <<= 1) {
                u64 q = __shfl_xor(g, o, 64);
                if (q > g) g = q;
            }
        }

        const int widx = (int)~(unsigned)g;
        if (r == 0 && t == 0) out[(size_t)b * NPTS + k] = widx;
        // uniform address across lanes: one transaction per wave, L3-hot
        sx = P[(size_t)widx * 3 + 0];
        sy = P[(size_t)widx * 3 + 1];
        sz = P[(size_t)widx * 3 + 2];
    }
}

extern "C" void kernel_launch(void* const* d_in, const int* in_sizes, int n_in,
                              void* d_out, int out_size, void* d_ws, size_t ws_size,
                              hipStream_t stream)
{
    const float* pos     = (const float*)d_in[0];
    const int*   start_p = (const int*)d_in[1];
    int*         out     = (int*)d_out;
    u64*         slots   = (u64*)d_ws;

    const size_t need32 = (size_t)NB * NPTS * NSLOT * sizeof(u64);  // 16 MB
    const size_t need4  = (size_t)NB * NPTS * WPB * sizeof(u64);    //  2 MB

    void* args[] = { (void*)&pos, (void*)&start_p, (void*)&out, (void*)&slots };

    if (ws_size >= need32) {
        hipMemsetAsync(d_ws, 0, need32, stream);
        hipError_t e = hipLaunchCooperativeKernel(
            (const void*)fps_kernel<true>, dim3(NB * WPB), dim3(TPB),
            args, 0, stream);
        if (e != hipSuccess)
            fps_kernel<true><<<dim3(NB * WPB), dim3(TPB), 0, stream>>>(
                pos, start_p, out, slots);
    } else {
        hipMemsetAsync(d_ws, 0, need4, stream);
        hipError_t e = hipLaunchCooperativeKernel(
            (const void*)fps_kernel<false>, dim3(NB * WPB), dim3(TPB),
            args, 0, stream);
        if (e != hipSuccess)
            fps_kernel<false><<<dim3(NB * WPB), dim3(TPB), 0, stream>>>(
                pos, start_p, out, slots);
    }
}